// Round 1
// baseline (1065.763 us; speedup 1.0000x reference)
//
#include <hip/hip_runtime.h>
#include <math.h>

#define BB 8192
#define CC 5000
#define KTOP 20
#define MAXP 4096
#define MARGIN 0.5
#define ALPHA 0.5

// ws layout:
// [0..23]   double acc[3] : bce_sum, dp, dn
// [24..27]  int n_min
// [32..]    int counts[CC]
// then      int flags[CC]
// then      int minor[CC]
#define WS_ACC(ws)    ((double*)(ws))
#define WS_NMIN(ws)   ((int*)((char*)(ws) + 24))
#define WS_COUNTS(ws) ((int*)((char*)(ws) + 32))
#define WS_FLAGS(ws)  ((int*)((char*)(ws) + 32 + CC*4))
#define WS_MINOR(ws)  ((int*)((char*)(ws) + 32 + 2*CC*4))

__global__ void init_kernel(double* acc, int* nmin, int* counts) {
    int gid = blockIdx.x * blockDim.x + threadIdx.x;
    if (gid == 0) { acc[0] = 0.0; acc[1] = 0.0; acc[2] = 0.0; *nmin = 0; }
    for (int i = gid; i < CC; i += gridDim.x * blockDim.x) counts[i] = 0;
}

__device__ __forceinline__ float bce_term(float l, float t) {
    return fmaxf(l, 0.0f) - l * t + log1pf(expf(-fabsf(l)));
}

// Fused: BCE partial sum (f64) + per-class positive counts.
// C = 5000 = 1250 float4 per row. grid = (5, 256), block = 256, 32 rows per y-block.
__global__ __launch_bounds__(256)
void bce_counts_kernel(const float* __restrict__ logits, const float* __restrict__ target,
                       double* __restrict__ acc, int* __restrict__ counts) {
    int tid = threadIdx.x;
    int c4 = blockIdx.x * 256 + tid;            // float4 column index (0..1249)
    int r0 = blockIdx.y * 32;
    double bce = 0.0;
    int cnt0 = 0, cnt1 = 0, cnt2 = 0, cnt3 = 0;
    if (c4 < 1250) {
        const float4* L = (const float4*)logits;
        const float4* T = (const float4*)target;
        for (int r = r0; r < r0 + 32; ++r) {
            float4 l = L[(size_t)r * 1250 + c4];
            float4 t = T[(size_t)r * 1250 + c4];
            bce += (double)bce_term(l.x, t.x) + (double)bce_term(l.y, t.y)
                 + (double)bce_term(l.z, t.z) + (double)bce_term(l.w, t.w);
            cnt0 += (t.x == 1.0f); cnt1 += (t.y == 1.0f);
            cnt2 += (t.z == 1.0f); cnt3 += (t.w == 1.0f);
        }
        int c = c4 * 4;
        if (cnt0) atomicAdd(&counts[c + 0], cnt0);
        if (cnt1) atomicAdd(&counts[c + 1], cnt1);
        if (cnt2) atomicAdd(&counts[c + 2], cnt2);
        if (cnt3) atomicAdd(&counts[c + 3], cnt3);
    }
    __shared__ double sd[256];
    sd[tid] = bce;
    __syncthreads();
    for (int s = 128; s > 0; s >>= 1) {
        if (tid < s) sd[tid] += sd[tid + s];
        __syncthreads();
    }
    if (tid == 0) atomicAdd(&acc[0], sd[0]);
}

// Minority selection: class j kept iff count_j > 1 AND
// sum_k count_k * [(count_k,k) <=lex (count_j,j)] <= BB/2.
// This reproduces stable-argsort + cumsum <= 0.5*batch + count>1 filter.
__global__ __launch_bounds__(256)
void minority_flag_kernel(const int* __restrict__ counts, int* __restrict__ flags) {
    __shared__ int sc[CC];
    int tid = threadIdx.x;
    for (int i = tid; i < CC; i += 256) sc[i] = counts[i];
    __syncthreads();
    int j = blockIdx.x * 256 + tid;
    if (j < CC) {
        int cj = sc[j];
        int flag = 0;
        if (cj > 1) {
            long long cum = 0;
            for (int k = 0; k < CC; ++k) {
                int ck = sc[k];
                if (ck < cj || (ck == cj && k <= j)) cum += ck;
            }
            flag = (cum <= (long long)(BB / 2));
        }
        flags[j] = flag;
    }
}

__global__ void compact_kernel(const int* __restrict__ flags, int* __restrict__ minor,
                               int* __restrict__ nmin) {
    if (blockIdx.x == 0 && threadIdx.x == 0) {
        int n = 0;
        for (int j = 0; j < CC; ++j)
            if (flags[j]) minor[n++] = j;
        *nmin = n;
    }
}

// One block per minority class (strided). Computes dp/dn contributions.
__global__ __launch_bounds__(256)
void crl_kernel(const float* __restrict__ logits, const float* __restrict__ target,
                const int* __restrict__ minor, const int* __restrict__ nmin,
                double* __restrict__ acc) {
    __shared__ float pos[MAXP];
    __shared__ float neglist[256 * KTOP];
    __shared__ float negsel[KTOP];
    __shared__ double sd[256];
    __shared__ float candv[256];
    __shared__ int candi[256];
    __shared__ int head[256];
    __shared__ int pcount;
    int tid = threadIdx.x;
    int nm = *nmin;

    for (int m = blockIdx.x; m < nm; m += gridDim.x) {
        int j = minor[m];
        if (tid == 0) pcount = 0;
        for (int i = 0; i < KTOP; ++i) neglist[tid * KTOP + i] = INFINITY;
        __syncthreads();

        // scan column j
        for (int r = tid; r < BB; r += 256) {
            float t = target[(size_t)r * CC + j];
            float x = logits[(size_t)r * CC + j];
            float e = expf(-fabsf(x));
            float s = (x >= 0.0f) ? 1.0f / (1.0f + e) : e / (1.0f + e);
            if (t == 1.0f) {
                int slot = atomicAdd(&pcount, 1);
                if (slot < MAXP) pos[slot] = s;
            } else {
                float* lst = &neglist[tid * KTOP];
                if (s < lst[KTOP - 1]) {
                    int p = KTOP - 1;
                    while (p > 0 && lst[p - 1] > s) { lst[p] = lst[p - 1]; --p; }
                    lst[p] = s;
                }
            }
        }
        __syncthreads();
        int cp = min(pcount, MAXP);   // guaranteed >= 2 and <= 4096 by selection rule

        // pad positives to pow2 and bitonic sort ascending
        int n = 1;
        while (n < cp) n <<= 1;
        for (int i = cp + tid; i < n; i += 256) pos[i] = INFINITY;
        __syncthreads();
        for (int k = 2; k <= n; k <<= 1) {
            for (int jj = k >> 1; jj > 0; jj >>= 1) {
                for (int i = tid; i < n; i += 256) {
                    int ixj = i ^ jj;
                    if (ixj > i) {
                        float a = pos[i], b = pos[ixj];
                        bool up = ((i & k) == 0);
                        if (up ? (a > b) : (a < b)) { pos[i] = b; pos[ixj] = a; }
                    }
                }
                __syncthreads();
            }
        }

        // merge per-thread sorted min-20 lists -> global 20 smallest negatives
        head[tid] = 0;
        __syncthreads();
        for (int round = 0; round < KTOP; ++round) {
            float v = (head[tid] < KTOP) ? neglist[tid * KTOP + head[tid]] : INFINITY;
            candv[tid] = v; candi[tid] = tid;
            __syncthreads();
            for (int s = 128; s > 0; s >>= 1) {
                if (tid < s && candv[tid + s] < candv[tid]) {
                    candv[tid] = candv[tid + s]; candi[tid] = candi[tid + s];
                }
                __syncthreads();
            }
            if (tid == 0) negsel[round] = candv[0];
            if (tid == candi[0]) head[tid]++;
            __syncthreads();
        }

        int np_a = min(KTOP, cp - 1);
        int n_n = min(KTOP, BB - cp);   // always 20 here

        // pos_sum: per sorted anchor r, window [0..np_a] if r<=np_a else [0..np_a-1]
        // (excluded self term is |x-x|=0, so including it is equivalent)
        double lsum = 0.0;
        for (int r = tid; r < cp; r += 256) {
            float v = pos[r];
            int L = (r <= np_a) ? np_a : np_a - 1;
            double s = 0.0;
            for (int l = 0; l <= L; ++l) s += (double)fabsf(v - pos[l]);
            lsum += s;
        }
        sd[tid] = lsum;
        __syncthreads();
        for (int s = 128; s > 0; s >>= 1) {
            if (tid < s) sd[tid] += sd[tid + s];
            __syncthreads();
        }
        double pos_sum = sd[0];
        __syncthreads();

        // neg_sum: all anchors vs 20 smallest negatives
        lsum = 0.0;
        for (int r = tid; r < cp; r += 256) {
            float v = pos[r];
            double s = 0.0;
            for (int l = 0; l < n_n; ++l) s += (double)fabsf(v - negsel[l]);
            lsum += s;
        }
        sd[tid] = lsum;
        __syncthreads();
        for (int s = 128; s > 0; s >>= 1) {
            if (tid < s) sd[tid] += sd[tid + s];
            __syncthreads();
        }
        if (tid == 0) {
            atomicAdd(&acc[1], (double)n_n * pos_sum);
            atomicAdd(&acc[2], (double)np_a * sd[0]);
        }
        __syncthreads();
    }
}

__global__ void finalize_kernel(const double* __restrict__ acc, const int* __restrict__ nmin,
                                float* __restrict__ out) {
    if (blockIdx.x == 0 && threadIdx.x == 0) {
        double bce = acc[0] / ((double)BB * (double)CC);
        double result;
        if (*nmin > 0) {
            double crl = acc[1] - acc[2] + MARGIN;
            if (crl < 0.0) crl = 0.0;
            result = ALPHA * crl + (1.0 - ALPHA) * bce;
        } else {
            result = bce;
        }
        out[0] = (float)result;
    }
}

extern "C" void kernel_launch(void* const* d_in, const int* in_sizes, int n_in,
                              void* d_out, int out_size, void* d_ws, size_t ws_size,
                              hipStream_t stream) {
    const float* logits = (const float*)d_in[0];
    const float* target = (const float*)d_in[1];
    float* out = (float*)d_out;

    double* acc  = WS_ACC(d_ws);
    int* nmin    = WS_NMIN(d_ws);
    int* counts  = WS_COUNTS(d_ws);
    int* flags   = WS_FLAGS(d_ws);
    int* minor   = WS_MINOR(d_ws);

    init_kernel<<<20, 256, 0, stream>>>(acc, nmin, counts);
    bce_counts_kernel<<<dim3(5, 256), 256, 0, stream>>>(logits, target, acc, counts);
    minority_flag_kernel<<<(CC + 255) / 256, 256, 0, stream>>>(counts, flags);
    compact_kernel<<<1, 64, 0, stream>>>(flags, minor, nmin);
    crl_kernel<<<128, 256, 0, stream>>>(logits, target, minor, nmin, acc);
    finalize_kernel<<<1, 64, 0, stream>>>(acc, nmin, out);
}

// Round 2
// 451.521 us; speedup vs baseline: 2.3604x; 2.3604x over previous
//
#include <hip/hip_runtime.h>
#include <math.h>

#define BB 8192
#define CC 5000
#define KTOP 20
#define MAXP 4096
#define MARGIN 0.5
#define ALPHA 0.5

// ws layout:
// [0..23]   double acc[3] : bce_sum, dp, dn
// [24..27]  int n_min
// [32..]    int counts[CC]
// then      int flags[CC]
// then      int minor[CC]
#define WS_ACC(ws)    ((double*)(ws))
#define WS_NMIN(ws)   ((int*)((char*)(ws) + 24))
#define WS_COUNTS(ws) ((int*)((char*)(ws) + 32))
#define WS_FLAGS(ws)  ((int*)((char*)(ws) + 32 + CC*4))
#define WS_MINOR(ws)  ((int*)((char*)(ws) + 32 + 2*CC*4))

__global__ void init_kernel(double* acc, int* nmin, int* counts) {
    int gid = blockIdx.x * blockDim.x + threadIdx.x;
    if (gid == 0) { acc[0] = 0.0; acc[1] = 0.0; acc[2] = 0.0; *nmin = 0; }
    for (int i = gid; i < CC; i += gridDim.x * blockDim.x) counts[i] = 0;
}

__device__ __forceinline__ float bce_term(float l, float t) {
    return fmaxf(l, 0.0f) - l * t + log1pf(expf(-fabsf(l)));
}

// Fused: BCE partial sum (f64) + per-class positive counts.
// C = 5000 = 1250 float4 per row. grid = (5, 256), block = 256, 32 rows per y-block.
__global__ __launch_bounds__(256)
void bce_counts_kernel(const float* __restrict__ logits, const float* __restrict__ target,
                       double* __restrict__ acc, int* __restrict__ counts) {
    int tid = threadIdx.x;
    int c4 = blockIdx.x * 256 + tid;            // float4 column index (0..1249)
    int r0 = blockIdx.y * 32;
    double bce = 0.0;
    int cnt0 = 0, cnt1 = 0, cnt2 = 0, cnt3 = 0;
    if (c4 < 1250) {
        const float4* L = (const float4*)logits;
        const float4* T = (const float4*)target;
        for (int r = r0; r < r0 + 32; ++r) {
            float4 l = L[(size_t)r * 1250 + c4];
            float4 t = T[(size_t)r * 1250 + c4];
            bce += (double)bce_term(l.x, t.x) + (double)bce_term(l.y, t.y)
                 + (double)bce_term(l.z, t.z) + (double)bce_term(l.w, t.w);
            cnt0 += (t.x == 1.0f); cnt1 += (t.y == 1.0f);
            cnt2 += (t.z == 1.0f); cnt3 += (t.w == 1.0f);
        }
        int c = c4 * 4;
        if (cnt0) atomicAdd(&counts[c + 0], cnt0);
        if (cnt1) atomicAdd(&counts[c + 1], cnt1);
        if (cnt2) atomicAdd(&counts[c + 2], cnt2);
        if (cnt3) atomicAdd(&counts[c + 3], cnt3);
    }
    __shared__ double sd[256];
    sd[tid] = bce;
    __syncthreads();
    for (int s = 128; s > 0; s >>= 1) {
        if (tid < s) sd[tid] += sd[tid + s];
        __syncthreads();
    }
    if (tid == 0) atomicAdd(&acc[0], sd[0]);
}

// Minority selection: class j kept iff count_j > 1 AND
// sum_k count_k * [(count_k,k) <=lex (count_j,j)] <= BB/2.
// One WAVE per class: lane-strided scan over LDS counts, shfl reduce.
__global__ __launch_bounds__(256)
void minority_flag_kernel(const int* __restrict__ counts, int* __restrict__ flags) {
    __shared__ int sc[CC];
    int tid = threadIdx.x;
    for (int i = tid; i < CC; i += 256) sc[i] = counts[i];
    __syncthreads();
    int wave = tid >> 6;
    int lane = tid & 63;
    int j = blockIdx.x * 4 + wave;        // class id (grid = 1250 -> covers 0..4999)
    if (j >= CC) return;
    int cj = sc[j];
    int flag = 0;
    if (cj > 1) {
        int cum = 0;
        for (int k = lane; k < CC; k += 64) {
            int ck = sc[k];
            if (ck < cj || (ck == cj && k <= j)) cum += ck;
        }
        for (int off = 32; off > 0; off >>= 1) cum += __shfl_down(cum, off);
        flag = (cum <= (BB / 2));
    }
    if (lane == 0) flags[j] = flag;
}

// Parallel compact: 256 threads x 20-class chunks, block prefix scan.
__global__ __launch_bounds__(256)
void compact_kernel(const int* __restrict__ flags, int* __restrict__ minor,
                    int* __restrict__ nmin) {
    const int CH = 20;   // 256*20 >= 5000
    int tid = threadIdx.x;
    int f[CH];
    int c = 0;
    #pragma unroll
    for (int i = 0; i < CH; ++i) {
        int j = tid * CH + i;
        int v = (j < CC) ? flags[j] : 0;
        f[i] = v; c += v;
    }
    __shared__ int ssum[256];
    ssum[tid] = c;
    __syncthreads();
    for (int off = 1; off < 256; off <<= 1) {
        int v = ssum[tid];
        int add = (tid >= off) ? ssum[tid - off] : 0;
        __syncthreads();
        ssum[tid] = v + add;
        __syncthreads();
    }
    int pos = ssum[tid] - c;   // exclusive prefix
    #pragma unroll
    for (int i = 0; i < CH; ++i) {
        if (f[i]) minor[pos++] = tid * CH + i;
    }
    if (tid == 255) *nmin = ssum[255];
}

// One block per minority class (strided). Computes dp/dn contributions.
__global__ __launch_bounds__(256)
void crl_kernel(const float* __restrict__ logits, const float* __restrict__ target,
                const int* __restrict__ minor, const int* __restrict__ nmin,
                double* __restrict__ acc) {
    __shared__ float pos[MAXP];
    __shared__ float neglist[256 * KTOP];
    __shared__ float negwave[4 * KTOP];
    __shared__ float negsel[KTOP];
    __shared__ double sd[256];
    __shared__ int pcount;
    int tid = threadIdx.x;
    int lane = tid & 63;
    int wave = tid >> 6;
    int nm = *nmin;

    for (int m = blockIdx.x; m < nm; m += gridDim.x) {
        int j = minor[m];
        if (tid == 0) pcount = 0;
        for (int i = 0; i < KTOP; ++i) neglist[tid * KTOP + i] = INFINITY;
        __syncthreads();

        // scan column j: register-stage loads in chunks of 8 rows so they pipeline
        const float* tcol = target + j;
        const float* xcol = logits + j;
        for (int base = 0; base < 32; base += 8) {
            float tv[8], xv[8];
            #pragma unroll
            for (int i = 0; i < 8; ++i) {
                size_t r = (size_t)(tid + (base + i) * 256);
                tv[i] = tcol[r * CC];
                xv[i] = xcol[r * CC];
            }
            #pragma unroll
            for (int i = 0; i < 8; ++i) {
                float x = xv[i];
                float e = expf(-fabsf(x));
                float s = (x >= 0.0f) ? 1.0f / (1.0f + e) : e / (1.0f + e);
                if (tv[i] == 1.0f) {
                    int slot = atomicAdd(&pcount, 1);
                    if (slot < MAXP) pos[slot] = s;
                } else {
                    float* lst = &neglist[tid * KTOP];
                    if (s < lst[KTOP - 1]) {
                        int p = KTOP - 1;
                        while (p > 0 && lst[p - 1] > s) { lst[p] = lst[p - 1]; --p; }
                        lst[p] = s;
                    }
                }
            }
        }
        __syncthreads();
        int cp = min(pcount, MAXP);   // selection rule guarantees 2 <= cp <= 4096

        // pad positives to pow2 and bitonic sort ascending
        int n = 1;
        while (n < cp) n <<= 1;
        for (int i = cp + tid; i < n; i += 256) pos[i] = INFINITY;
        __syncthreads();
        for (int k = 2; k <= n; k <<= 1) {
            for (int jj = k >> 1; jj > 0; jj >>= 1) {
                for (int i = tid; i < n; i += 256) {
                    int ixj = i ^ jj;
                    if (ixj > i) {
                        float a = pos[i], b = pos[ixj];
                        bool up = ((i & k) == 0);
                        if (up ? (a > b) : (a < b)) { pos[i] = b; pos[ixj] = a; }
                    }
                }
                __syncthreads();
            }
        }

        // wave-level merge of per-thread sorted top-20 lists (shfl argmin, no syncs)
        {
            int head = 0;
            for (int round = 0; round < KTOP; ++round) {
                float v = (head < KTOP) ? neglist[tid * KTOP + head] : INFINITY;
                int idx = lane;
                for (int off = 32; off > 0; off >>= 1) {
                    float ov = __shfl_xor(v, off);
                    int oi = __shfl_xor(idx, off);
                    if (ov < v || (ov == v && oi < idx)) { v = ov; idx = oi; }
                }
                if (lane == 0) negwave[wave * KTOP + round] = v;
                if (lane == idx) head++;
            }
        }
        __syncthreads();
        // final serial 4-way merge of sorted wave lists (thread 0, 80 LDS reads)
        if (tid == 0) {
            int h0 = 0, h1 = 0, h2 = 0, h3 = 0;
            for (int r = 0; r < KTOP; ++r) {
                float v0 = (h0 < KTOP) ? negwave[0 * KTOP + h0] : INFINITY;
                float v1 = (h1 < KTOP) ? negwave[1 * KTOP + h1] : INFINITY;
                float v2 = (h2 < KTOP) ? negwave[2 * KTOP + h2] : INFINITY;
                float v3 = (h3 < KTOP) ? negwave[3 * KTOP + h3] : INFINITY;
                float best = v0; int bi = 0;
                if (v1 < best) { best = v1; bi = 1; }
                if (v2 < best) { best = v2; bi = 2; }
                if (v3 < best) { best = v3; bi = 3; }
                negsel[r] = best;
                if (bi == 0) h0++; else if (bi == 1) h1++; else if (bi == 2) h2++; else h3++;
            }
        }
        __syncthreads();

        int np_a = min(KTOP, cp - 1);
        int n_n = min(KTOP, BB - cp);   // always 20 here

        // pos_sum: per sorted anchor r, window [0..np_a] if r<=np_a else [0..np_a-1]
        // (excluded self term is |x-x|=0, so including it is equivalent)
        double lsum = 0.0;
        for (int r = tid; r < cp; r += 256) {
            float v = pos[r];
            int L = (r <= np_a) ? np_a : np_a - 1;
            double s = 0.0;
            for (int l = 0; l <= L; ++l) s += (double)fabsf(v - pos[l]);
            lsum += s;
        }
        sd[tid] = lsum;
        __syncthreads();
        for (int s = 128; s > 0; s >>= 1) {
            if (tid < s) sd[tid] += sd[tid + s];
            __syncthreads();
        }
        double pos_sum = sd[0];
        __syncthreads();

        // neg_sum: all anchors vs 20 smallest negatives
        lsum = 0.0;
        for (int r = tid; r < cp; r += 256) {
            float v = pos[r];
            double s = 0.0;
            for (int l = 0; l < n_n; ++l) s += (double)fabsf(v - negsel[l]);
            lsum += s;
        }
        sd[tid] = lsum;
        __syncthreads();
        for (int s = 128; s > 0; s >>= 1) {
            if (tid < s) sd[tid] += sd[tid + s];
            __syncthreads();
        }
        if (tid == 0) {
            atomicAdd(&acc[1], (double)n_n * pos_sum);
            atomicAdd(&acc[2], (double)np_a * sd[0]);
        }
        __syncthreads();
    }
}

__global__ void finalize_kernel(const double* __restrict__ acc, const int* __restrict__ nmin,
                                float* __restrict__ out) {
    if (blockIdx.x == 0 && threadIdx.x == 0) {
        double bce = acc[0] / ((double)BB * (double)CC);
        double result;
        if (*nmin > 0) {
            double crl = acc[1] - acc[2] + MARGIN;
            if (crl < 0.0) crl = 0.0;
            result = ALPHA * crl + (1.0 - ALPHA) * bce;
        } else {
            result = bce;
        }
        out[0] = (float)result;
    }
}

extern "C" void kernel_launch(void* const* d_in, const int* in_sizes, int n_in,
                              void* d_out, int out_size, void* d_ws, size_t ws_size,
                              hipStream_t stream) {
    const float* logits = (const float*)d_in[0];
    const float* target = (const float*)d_in[1];
    float* out = (float*)d_out;

    double* acc  = WS_ACC(d_ws);
    int* nmin    = WS_NMIN(d_ws);
    int* counts  = WS_COUNTS(d_ws);
    int* flags   = WS_FLAGS(d_ws);
    int* minor   = WS_MINOR(d_ws);

    init_kernel<<<20, 256, 0, stream>>>(acc, nmin, counts);
    bce_counts_kernel<<<dim3(5, 256), 256, 0, stream>>>(logits, target, acc, counts);
    minority_flag_kernel<<<1250, 256, 0, stream>>>(counts, flags);
    compact_kernel<<<1, 256, 0, stream>>>(flags, minor, nmin);
    crl_kernel<<<64, 256, 0, stream>>>(logits, target, minor, nmin, acc);
    finalize_kernel<<<1, 64, 0, stream>>>(acc, nmin, out);
}

// Round 3
// 439.788 us; speedup vs baseline: 2.4234x; 1.0267x over previous
//
#include <hip/hip_runtime.h>
#include <math.h>

#define BB 8192
#define CC 5000
#define KTOP 20
#define MAXP 4096
#define MARGIN 0.5
#define ALPHA 0.5

// ws layout:
// [0..23]   double acc[3] : bce_sum, dp, dn
// [24..27]  int n_min
// [32..]    int counts[CC]
// then      int flags[CC]
// then      int minor[CC]
#define WS_ACC(ws)    ((double*)(ws))
#define WS_NMIN(ws)   ((int*)((char*)(ws) + 24))
#define WS_COUNTS(ws) ((int*)((char*)(ws) + 32))
#define WS_FLAGS(ws)  ((int*)((char*)(ws) + 32 + CC*4))
#define WS_MINOR(ws)  ((int*)((char*)(ws) + 32 + 2*CC*4))

__global__ void init_kernel(double* acc, int* nmin, int* counts) {
    int gid = blockIdx.x * blockDim.x + threadIdx.x;
    if (gid == 0) { acc[0] = 0.0; acc[1] = 0.0; acc[2] = 0.0; *nmin = 0; }
    for (int i = gid; i < CC; i += gridDim.x * blockDim.x) counts[i] = 0;
}

// fast BCE term: max(l,0) - l*t + log(1+exp(-|l|)) via HW transcendentals.
// rel err ~1e-6 -- threshold is 8e-3 absolute, huge margin (R2 absmax was 0.0 with libm).
__device__ __forceinline__ float bce_term_fast(float l, float t) {
    float e = __expf(-fabsf(l));          // v_exp_f32
    float sp = __logf(1.0f + e);          // v_log_f32
    return fmaxf(l, 0.0f) - l * t + sp;
}

// Fused: BCE partial sum + per-class positive counts.
// C = 5000 = 1250 float4 per row. grid = (5, 256), block = 256, 32 rows per y-block.
__global__ __launch_bounds__(256)
void bce_counts_kernel(const float* __restrict__ logits, const float* __restrict__ target,
                       double* __restrict__ acc, int* __restrict__ counts) {
    int tid = threadIdx.x;
    int c4 = blockIdx.x * 256 + tid;            // float4 column index (0..1249)
    int r0 = blockIdx.y * 32;
    float bce = 0.0f;                            // 128 terms/thread: float is plenty
    int cnt0 = 0, cnt1 = 0, cnt2 = 0, cnt3 = 0;
    if (c4 < 1250) {
        const float4* L = (const float4*)logits;
        const float4* T = (const float4*)target;
        for (int r = r0; r < r0 + 32; ++r) {
            float4 l = L[(size_t)r * 1250 + c4];
            float4 t = T[(size_t)r * 1250 + c4];
            bce += bce_term_fast(l.x, t.x) + bce_term_fast(l.y, t.y)
                 + bce_term_fast(l.z, t.z) + bce_term_fast(l.w, t.w);
            cnt0 += (t.x == 1.0f); cnt1 += (t.y == 1.0f);
            cnt2 += (t.z == 1.0f); cnt3 += (t.w == 1.0f);
        }
        int c = c4 * 4;
        if (cnt0) atomicAdd(&counts[c + 0], cnt0);
        if (cnt1) atomicAdd(&counts[c + 1], cnt1);
        if (cnt2) atomicAdd(&counts[c + 2], cnt2);
        if (cnt3) atomicAdd(&counts[c + 3], cnt3);
    }
    __shared__ double sd[256];
    sd[tid] = (double)bce;
    __syncthreads();
    for (int s = 128; s > 0; s >>= 1) {
        if (tid < s) sd[tid] += sd[tid + s];
        __syncthreads();
    }
    if (tid == 0) atomicAdd(&acc[0], sd[0]);
}

// Minority selection: class j kept iff count_j > 1 AND
// sum_k count_k * [(count_k,k) <=lex (count_j,j)] <= BB/2.
// One WAVE per class: lane-strided scan over LDS counts, shfl reduce.
__global__ __launch_bounds__(256)
void minority_flag_kernel(const int* __restrict__ counts, int* __restrict__ flags) {
    __shared__ int sc[CC];
    int tid = threadIdx.x;
    for (int i = tid; i < CC; i += 256) sc[i] = counts[i];
    __syncthreads();
    int wave = tid >> 6;
    int lane = tid & 63;
    int j = blockIdx.x * 4 + wave;        // class id (grid = 1250 -> covers 0..4999)
    if (j >= CC) return;
    int cj = sc[j];
    int flag = 0;
    if (cj > 1) {
        int cum = 0;
        for (int k = lane; k < CC; k += 64) {
            int ck = sc[k];
            if (ck < cj || (ck == cj && k <= j)) cum += ck;
        }
        for (int off = 32; off > 0; off >>= 1) cum += __shfl_down(cum, off);
        flag = (cum <= (BB / 2));
    }
    if (lane == 0) flags[j] = flag;
}

// Parallel compact: 256 threads x 20-class chunks, block prefix scan.
__global__ __launch_bounds__(256)
void compact_kernel(const int* __restrict__ flags, int* __restrict__ minor,
                    int* __restrict__ nmin) {
    const int CH = 20;   // 256*20 >= 5000
    int tid = threadIdx.x;
    int f[CH];
    int c = 0;
    #pragma unroll
    for (int i = 0; i < CH; ++i) {
        int j = tid * CH + i;
        int v = (j < CC) ? flags[j] : 0;
        f[i] = v; c += v;
    }
    __shared__ int ssum[256];
    ssum[tid] = c;
    __syncthreads();
    for (int off = 1; off < 256; off <<= 1) {
        int v = ssum[tid];
        int add = (tid >= off) ? ssum[tid - off] : 0;
        __syncthreads();
        ssum[tid] = v + add;
        __syncthreads();
    }
    int pos = ssum[tid] - c;   // exclusive prefix
    #pragma unroll
    for (int i = 0; i < CH; ++i) {
        if (f[i]) minor[pos++] = tid * CH + i;
    }
    if (tid == 255) *nmin = ssum[255];
}

// One block per minority class (strided). Computes dp/dn contributions.
__global__ __launch_bounds__(256)
void crl_kernel(const float* __restrict__ logits, const float* __restrict__ target,
                const int* __restrict__ minor, const int* __restrict__ nmin,
                double* __restrict__ acc) {
    __shared__ float pos[MAXP];
    __shared__ float neglist[256 * KTOP];
    __shared__ float negwave[4 * KTOP];
    __shared__ float negsel[KTOP];
    __shared__ double sd[256];
    __shared__ int pcount;
    int tid = threadIdx.x;
    int lane = tid & 63;
    int wave = tid >> 6;
    int nm = *nmin;

    for (int m = blockIdx.x; m < nm; m += gridDim.x) {
        int j = minor[m];
        if (tid == 0) pcount = 0;
        for (int i = 0; i < KTOP; ++i) neglist[tid * KTOP + i] = INFINITY;
        __syncthreads();

        // scan column j: stage ALL 32 rows/thread (64 loads in flight) so the
        // strided-gather latency is paid once, not 4x.
        const float* tcol = target + j;
        const float* xcol = logits + j;
        float tv[32], xv[32];
        #pragma unroll
        for (int i = 0; i < 32; ++i) {
            size_t r = (size_t)(tid + i * 256);
            tv[i] = tcol[r * CC];
            xv[i] = xcol[r * CC];
        }
        #pragma unroll
        for (int i = 0; i < 32; ++i) {
            float x = xv[i];
            float e = __expf(-fabsf(x));
            float inv = __builtin_amdgcn_rcpf(1.0f + e);   // ~1ulp
            float s = (x >= 0.0f) ? inv : e * inv;
            if (tv[i] == 1.0f) {
                int slot = atomicAdd(&pcount, 1);
                if (slot < MAXP) pos[slot] = s;
            } else {
                float* lst = &neglist[tid * KTOP];
                if (s < lst[KTOP - 1]) {
                    int p = KTOP - 1;
                    while (p > 0 && lst[p - 1] > s) { lst[p] = lst[p - 1]; --p; }
                    lst[p] = s;
                }
            }
        }
        __syncthreads();
        int cp = min(pcount, MAXP);   // selection rule guarantees 2 <= cp <= 4096

        // pad positives to pow2 and bitonic sort ascending (cp ~ 25 in practice)
        int n = 1;
        while (n < cp) n <<= 1;
        for (int i = cp + tid; i < n; i += 256) pos[i] = INFINITY;
        __syncthreads();
        for (int k = 2; k <= n; k <<= 1) {
            for (int jj = k >> 1; jj > 0; jj >>= 1) {
                for (int i = tid; i < n; i += 256) {
                    int ixj = i ^ jj;
                    if (ixj > i) {
                        float a = pos[i], b = pos[ixj];
                        bool up = ((i & k) == 0);
                        if (up ? (a > b) : (a < b)) { pos[i] = b; pos[ixj] = a; }
                    }
                }
                __syncthreads();
            }
        }

        // wave-level merge of per-thread sorted top-20 lists (shfl argmin, no syncs)
        {
            int head = 0;
            for (int round = 0; round < KTOP; ++round) {
                float v = (head < KTOP) ? neglist[tid * KTOP + head] : INFINITY;
                int idx = lane;
                for (int off = 32; off > 0; off >>= 1) {
                    float ov = __shfl_xor(v, off);
                    int oi = __shfl_xor(idx, off);
                    if (ov < v || (ov == v && oi < idx)) { v = ov; idx = oi; }
                }
                if (lane == 0) negwave[wave * KTOP + round] = v;
                if (lane == idx) head++;
            }
        }
        __syncthreads();
        // final serial 4-way merge of sorted wave lists (thread 0, 80 LDS reads)
        if (tid == 0) {
            int h0 = 0, h1 = 0, h2 = 0, h3 = 0;
            for (int r = 0; r < KTOP; ++r) {
                float v0 = (h0 < KTOP) ? negwave[0 * KTOP + h0] : INFINITY;
                float v1 = (h1 < KTOP) ? negwave[1 * KTOP + h1] : INFINITY;
                float v2 = (h2 < KTOP) ? negwave[2 * KTOP + h2] : INFINITY;
                float v3 = (h3 < KTOP) ? negwave[3 * KTOP + h3] : INFINITY;
                float best = v0; int bi = 0;
                if (v1 < best) { best = v1; bi = 1; }
                if (v2 < best) { best = v2; bi = 2; }
                if (v3 < best) { best = v3; bi = 3; }
                negsel[r] = best;
                if (bi == 0) h0++; else if (bi == 1) h1++; else if (bi == 2) h2++; else h3++;
            }
        }
        __syncthreads();

        int np_a = min(KTOP, cp - 1);
        int n_n = min(KTOP, BB - cp);   // always 20 here

        // pos_sum: per sorted anchor r, window [0..np_a] if r<=np_a else [0..np_a-1]
        // (excluded self term is |x-x|=0, so including it is equivalent)
        double lsum = 0.0;
        for (int r = tid; r < cp; r += 256) {
            float v = pos[r];
            int L = (r <= np_a) ? np_a : np_a - 1;
            double s = 0.0;
            for (int l = 0; l <= L; ++l) s += (double)fabsf(v - pos[l]);
            lsum += s;
        }
        sd[tid] = lsum;
        __syncthreads();
        for (int s = 128; s > 0; s >>= 1) {
            if (tid < s) sd[tid] += sd[tid + s];
            __syncthreads();
        }
        double pos_sum = sd[0];
        __syncthreads();

        // neg_sum: all anchors vs 20 smallest negatives
        lsum = 0.0;
        for (int r = tid; r < cp; r += 256) {
            float v = pos[r];
            double s = 0.0;
            for (int l = 0; l < n_n; ++l) s += (double)fabsf(v - negsel[l]);
            lsum += s;
        }
        sd[tid] = lsum;
        __syncthreads();
        for (int s = 128; s > 0; s >>= 1) {
            if (tid < s) sd[tid] += sd[tid + s];
            __syncthreads();
        }
        if (tid == 0) {
            atomicAdd(&acc[1], (double)n_n * pos_sum);
            atomicAdd(&acc[2], (double)np_a * sd[0]);
        }
        __syncthreads();
    }
}

__global__ void finalize_kernel(const double* __restrict__ acc, const int* __restrict__ nmin,
                                float* __restrict__ out) {
    if (blockIdx.x == 0 && threadIdx.x == 0) {
        double bce = acc[0] / ((double)BB * (double)CC);
        double result;
        if (*nmin > 0) {
            double crl = acc[1] - acc[2] + MARGIN;
            if (crl < 0.0) crl = 0.0;
            result = ALPHA * crl + (1.0 - ALPHA) * bce;
        } else {
            result = bce;
        }
        out[0] = (float)result;
    }
}

extern "C" void kernel_launch(void* const* d_in, const int* in_sizes, int n_in,
                              void* d_out, int out_size, void* d_ws, size_t ws_size,
                              hipStream_t stream) {
    const float* logits = (const float*)d_in[0];
    const float* target = (const float*)d_in[1];
    float* out = (float*)d_out;

    double* acc  = WS_ACC(d_ws);
    int* nmin    = WS_NMIN(d_ws);
    int* counts  = WS_COUNTS(d_ws);
    int* flags   = WS_FLAGS(d_ws);
    int* minor   = WS_MINOR(d_ws);

    init_kernel<<<20, 256, 0, stream>>>(acc, nmin, counts);
    bce_counts_kernel<<<dim3(5, 256), 256, 0, stream>>>(logits, target, acc, counts);
    minority_flag_kernel<<<1250, 256, 0, stream>>>(counts, flags);
    compact_kernel<<<1, 256, 0, stream>>>(flags, minor, nmin);
    crl_kernel<<<64, 256, 0, stream>>>(logits, target, minor, nmin, acc);
    finalize_kernel<<<1, 64, 0, stream>>>(acc, nmin, out);
}

// Round 4
// 407.489 us; speedup vs baseline: 2.6154x; 1.0793x over previous
//
#include <hip/hip_runtime.h>
#include <math.h>

#define BB 8192
#define CC 5000
#define KTOP 20
#define MARGIN 0.5
#define ALPHA 0.5
#define NM_MAX 2048     // kept classes have count>=2 and sum<=4096 -> nm <= 2048
#define NRB 16          // row-blocks per class in gather
#define RPB 512         // rows per (class, row-block)

// ws layout (bytes):
// 0      acc[3] doubles : bce_sum, dp, dn
// 24     int nmin
// 32     counts[5000]
// 20032  flags[5000]
// 40032  minor[2048]
// 48224  posoff[2049]
// 56424  pcnt[2048]
// 64616  posbuf[4160] floats (sum of minority counts <= 4096)
// 81256  negblk[2048*16*20] floats (~2.6 MB)
#define WS_ACC(ws)    ((double*)(ws))
#define WS_NMIN(ws)   ((int*)((char*)(ws) + 24))
#define WS_COUNTS(ws) ((int*)((char*)(ws) + 32))
#define WS_FLAGS(ws)  ((int*)((char*)(ws) + 20032))
#define WS_MINOR(ws)  ((int*)((char*)(ws) + 40032))
#define WS_POSOFF(ws) ((int*)((char*)(ws) + 48224))
#define WS_PCNT(ws)   ((int*)((char*)(ws) + 56424))
#define WS_POSBUF(ws) ((float*)((char*)(ws) + 64616))
#define WS_NEGBLK(ws) ((float*)((char*)(ws) + 81256))

__global__ void init_kernel(double* acc, int* nmin, int* counts, int* pcnt) {
    int gid = blockIdx.x * blockDim.x + threadIdx.x;
    if (gid == 0) { acc[0] = 0.0; acc[1] = 0.0; acc[2] = 0.0; *nmin = 0; }
    for (int i = gid; i < CC; i += gridDim.x * blockDim.x) counts[i] = 0;
    for (int i = gid; i < NM_MAX; i += gridDim.x * blockDim.x) pcnt[i] = 0;
}

// fast BCE term via HW transcendentals (rel err ~1e-6, threshold 8e-3 abs)
__device__ __forceinline__ float bce_term_fast(float l, float t) {
    float e = __expf(-fabsf(l));
    float sp = __logf(1.0f + e);
    return fmaxf(l, 0.0f) - l * t + sp;
}

// Fused: BCE partial sum + per-class positive counts.
__global__ __launch_bounds__(256)
void bce_counts_kernel(const float* __restrict__ logits, const float* __restrict__ target,
                       double* __restrict__ acc, int* __restrict__ counts) {
    int tid = threadIdx.x;
    int c4 = blockIdx.x * 256 + tid;            // float4 column index (0..1249)
    int r0 = blockIdx.y * 32;
    float bce = 0.0f;
    int cnt0 = 0, cnt1 = 0, cnt2 = 0, cnt3 = 0;
    if (c4 < 1250) {
        const float4* L = (const float4*)logits;
        const float4* T = (const float4*)target;
        for (int r = r0; r < r0 + 32; ++r) {
            float4 l = L[(size_t)r * 1250 + c4];
            float4 t = T[(size_t)r * 1250 + c4];
            bce += bce_term_fast(l.x, t.x) + bce_term_fast(l.y, t.y)
                 + bce_term_fast(l.z, t.z) + bce_term_fast(l.w, t.w);
            cnt0 += (t.x == 1.0f); cnt1 += (t.y == 1.0f);
            cnt2 += (t.z == 1.0f); cnt3 += (t.w == 1.0f);
        }
        int c = c4 * 4;
        if (cnt0) atomicAdd(&counts[c + 0], cnt0);
        if (cnt1) atomicAdd(&counts[c + 1], cnt1);
        if (cnt2) atomicAdd(&counts[c + 2], cnt2);
        if (cnt3) atomicAdd(&counts[c + 3], cnt3);
    }
    __shared__ double sd[256];
    sd[tid] = (double)bce;
    __syncthreads();
    for (int s = 128; s > 0; s >>= 1) {
        if (tid < s) sd[tid] += sd[tid + s];
        __syncthreads();
    }
    if (tid == 0) atomicAdd(&acc[0], sd[0]);
}

// class j kept iff count_j>1 AND sum_k count_k*[(count_k,k) <=lex (count_j,j)] <= BB/2
__global__ __launch_bounds__(256)
void minority_flag_kernel(const int* __restrict__ counts, int* __restrict__ flags) {
    __shared__ int sc[CC];
    int tid = threadIdx.x;
    for (int i = tid; i < CC; i += 256) sc[i] = counts[i];
    __syncthreads();
    int wave = tid >> 6;
    int lane = tid & 63;
    int j = blockIdx.x * 4 + wave;
    if (j >= CC) return;
    int cj = sc[j];
    int flag = 0;
    if (cj > 1) {
        int cum = 0;
        for (int k = lane; k < CC; k += 64) {
            int ck = sc[k];
            if (ck < cj || (ck == cj && k <= j)) cum += ck;
        }
        for (int off = 32; off > 0; off >>= 1) cum += __shfl_down(cum, off);
        flag = (cum <= (BB / 2));
    }
    if (lane == 0) flags[j] = flag;
}

// Compact flags -> minor[], and build exclusive prefix posoff[] of minority counts.
__global__ __launch_bounds__(256)
void compact_kernel(const int* __restrict__ flags, const int* __restrict__ counts,
                    int* __restrict__ minor, int* __restrict__ nmin,
                    int* __restrict__ posoff) {
    const int CH = 20;   // 256*20 >= 5000
    int tid = threadIdx.x;
    __shared__ int ssum[256];
    __shared__ int sminor[NM_MAX];
    __shared__ int snm;

    int f[CH];
    int c = 0;
    #pragma unroll
    for (int i = 0; i < CH; ++i) {
        int j = tid * CH + i;
        int v = (j < CC) ? flags[j] : 0;
        f[i] = v; c += v;
    }
    ssum[tid] = c;
    __syncthreads();
    for (int off = 1; off < 256; off <<= 1) {
        int v = ssum[tid];
        int add = (tid >= off) ? ssum[tid - off] : 0;
        __syncthreads();
        ssum[tid] = v + add;
        __syncthreads();
    }
    int pos = ssum[tid] - c;   // exclusive prefix
    #pragma unroll
    for (int i = 0; i < CH; ++i) {
        if (f[i]) { sminor[pos] = tid * CH + i; minor[pos] = tid * CH + i; pos++; }
    }
    if (tid == 255) { snm = ssum[255]; *nmin = snm; }
    __syncthreads();
    int nm = snm;

    // phase 2: exclusive prefix of counts over minority classes
    const int CH2 = NM_MAX / 256;   // 8
    int cc2[CH2];
    int c2 = 0;
    #pragma unroll
    for (int i = 0; i < CH2; ++i) {
        int idx = tid * CH2 + i;
        int v = (idx < nm) ? counts[sminor[idx]] : 0;
        cc2[i] = v; c2 += v;
    }
    __syncthreads();
    ssum[tid] = c2;
    __syncthreads();
    for (int off = 1; off < 256; off <<= 1) {
        int v = ssum[tid];
        int add = (tid >= off) ? ssum[tid - off] : 0;
        __syncthreads();
        ssum[tid] = v + add;
        __syncthreads();
    }
    int p2 = ssum[tid] - c2;
    #pragma unroll
    for (int i = 0; i < CH2; ++i) {
        int idx = tid * CH2 + i;
        if (idx < nm) posoff[idx] = p2;
        p2 += cc2[i];
    }
    if (tid == 255) posoff[nm] = ssum[255];
}

// Gather: grid (64, NRB). Block (gx,gy) handles rows [gy*RPB, gy*RPB+RPB) of
// classes m = gx, gx+64, ... Scatters positives to posbuf, reduces its 512
// negatives to a sorted top-20 in negblk[m][gy][].
__global__ __launch_bounds__(256)
void crl_gather_kernel(const float* __restrict__ logits, const float* __restrict__ target,
                       const int* __restrict__ minor, const int* __restrict__ nmin,
                       const int* __restrict__ posoff, int* __restrict__ pcnt,
                       float* __restrict__ posbuf, float* __restrict__ negblk) {
    __shared__ float negwv[4 * KTOP];
    int tid = threadIdx.x;
    int lane = tid & 63;
    int wave = tid >> 6;
    int nm = *nmin;
    int gy = blockIdx.y;

    for (int m = blockIdx.x; m < nm; m += gridDim.x) {
        int j = minor[m];
        size_t rA = (size_t)gy * RPB + tid;
        size_t rB = rA + 256;
        float tA = target[rA * CC + j];
        float xA = logits[rA * CC + j];
        float tB = target[rB * CC + j];
        float xB = logits[rB * CC + j];

        float eA = __expf(-fabsf(xA));
        float iA = __builtin_amdgcn_rcpf(1.0f + eA);
        float sA = (xA >= 0.0f) ? iA : eA * iA;
        float eB = __expf(-fabsf(xB));
        float iB = __builtin_amdgcn_rcpf(1.0f + eB);
        float sB = (xB >= 0.0f) ? iB : eB * iB;

        int off = posoff[m];
        int cap = posoff[m + 1] - off;
        float v0, v1;
        if (tA == 1.0f) {
            int slot = atomicAdd(&pcnt[m], 1);
            if (slot < cap) posbuf[off + slot] = sA;
            v0 = INFINITY;
        } else v0 = sA;
        if (tB == 1.0f) {
            int slot = atomicAdd(&pcnt[m], 1);
            if (slot < cap) posbuf[off + slot] = sB;
            v1 = INFINITY;
        } else v1 = sB;
        if (v1 < v0) { float tmp = v0; v0 = v1; v1 = tmp; }

        // wave top-20 over 128 values (2/lane, sorted pair) via shfl argmin rounds
        int h = 0;
        for (int round = 0; round < KTOP; ++round) {
            float v = (h == 0) ? v0 : ((h == 1) ? v1 : INFINITY);
            int idx = lane;
            for (int o = 32; o > 0; o >>= 1) {
                float ov = __shfl_xor(v, o);
                int oi = __shfl_xor(idx, o);
                if (ov < v || (ov == v && oi < idx)) { v = ov; idx = oi; }
            }
            if (lane == 0) negwv[wave * KTOP + round] = v;
            if (lane == idx) h++;
        }
        __syncthreads();
        if (tid == 0) {
            // 4-way merge of sorted wave lists -> block top-20, sorted
            int h0 = 0, h1 = 0, h2 = 0, h3 = 0;
            float* dst = &negblk[((size_t)m * NRB + gy) * KTOP];
            for (int r = 0; r < KTOP; ++r) {
                float a0 = (h0 < KTOP) ? negwv[0 * KTOP + h0] : INFINITY;
                float a1 = (h1 < KTOP) ? negwv[1 * KTOP + h1] : INFINITY;
                float a2 = (h2 < KTOP) ? negwv[2 * KTOP + h2] : INFINITY;
                float a3 = (h3 < KTOP) ? negwv[3 * KTOP + h3] : INFINITY;
                float best = a0; int bi = 0;
                if (a1 < best) { best = a1; bi = 1; }
                if (a2 < best) { best = a2; bi = 2; }
                if (a3 < best) { best = a3; bi = 3; }
                dst[r] = best;
                if (bi == 0) h0++; else if (bi == 1) h1++; else if (bi == 2) h2++; else h3++;
            }
        }
        __syncthreads();
    }
}

// Reduce: one block per class (strided). Sort positives, merge block top-20s,
// compute dp/dn contributions.
__global__ __launch_bounds__(256)
void crl_reduce_kernel(const int* __restrict__ nmin, const int* __restrict__ posoff,
                       const float* __restrict__ posbuf, const float* __restrict__ negblk,
                       double* __restrict__ acc) {
    __shared__ float pos[4096];
    __shared__ float neg[512];
    __shared__ float negsel[KTOP];
    __shared__ double sd[256];
    int tid = threadIdx.x;
    int nm = *nmin;

    for (int m = blockIdx.x; m < nm; m += gridDim.x) {
        int off = posoff[m];
        int cp = posoff[m + 1] - off;            // >= 2, <= 4096

        // load positives, pad to pow2
        int n = 1;
        while (n < cp) n <<= 1;
        for (int i = tid; i < n; i += 256) pos[i] = (i < cp) ? posbuf[off + i] : INFINITY;
        // load negative candidates (NRB*KTOP = 320), pad to 512
        const float* src = &negblk[(size_t)m * NRB * KTOP];
        for (int i = tid; i < 512; i += 256) neg[i] = (i < NRB * KTOP) ? src[i] : INFINITY;
        __syncthreads();

        // bitonic sort neg[512]
        for (int k = 2; k <= 512; k <<= 1) {
            for (int jj = k >> 1; jj > 0; jj >>= 1) {
                for (int i = tid; i < 512; i += 256) {
                    int ixj = i ^ jj;
                    if (ixj > i) {
                        float a = neg[i], b = neg[ixj];
                        bool up = ((i & k) == 0);
                        if (up ? (a > b) : (a < b)) { neg[i] = b; neg[ixj] = a; }
                    }
                }
                __syncthreads();
            }
        }
        if (tid < KTOP) negsel[tid] = neg[tid];

        // bitonic sort pos[n]
        for (int k = 2; k <= n; k <<= 1) {
            for (int jj = k >> 1; jj > 0; jj >>= 1) {
                for (int i = tid; i < n; i += 256) {
                    int ixj = i ^ jj;
                    if (ixj > i) {
                        float a = pos[i], b = pos[ixj];
                        bool up = ((i & k) == 0);
                        if (up ? (a > b) : (a < b)) { pos[i] = b; pos[ixj] = a; }
                    }
                }
                __syncthreads();
            }
        }

        int np_a = min(KTOP, cp - 1);
        int n_n = min(KTOP, BB - cp);   // always 20 here

        // pos_sum: anchor r vs sorted window [0..np_a] (self term is 0)
        double lsum = 0.0;
        for (int r = tid; r < cp; r += 256) {
            float v = pos[r];
            int L = (r <= np_a) ? np_a : np_a - 1;
            double s = 0.0;
            for (int l = 0; l <= L; ++l) s += (double)fabsf(v - pos[l]);
            lsum += s;
        }
        sd[tid] = lsum;
        __syncthreads();
        for (int s = 128; s > 0; s >>= 1) {
            if (tid < s) sd[tid] += sd[tid + s];
            __syncthreads();
        }
        double pos_sum = sd[0];
        __syncthreads();

        // neg_sum: all anchors vs 20 smallest negatives
        lsum = 0.0;
        for (int r = tid; r < cp; r += 256) {
            float v = pos[r];
            double s = 0.0;
            for (int l = 0; l < n_n; ++l) s += (double)fabsf(v - negsel[l]);
            lsum += s;
        }
        sd[tid] = lsum;
        __syncthreads();
        for (int s = 128; s > 0; s >>= 1) {
            if (tid < s) sd[tid] += sd[tid + s];
            __syncthreads();
        }
        if (tid == 0) {
            atomicAdd(&acc[1], (double)n_n * pos_sum);
            atomicAdd(&acc[2], (double)np_a * sd[0]);
        }
        __syncthreads();
    }
}

__global__ void finalize_kernel(const double* __restrict__ acc, const int* __restrict__ nmin,
                                float* __restrict__ out) {
    if (blockIdx.x == 0 && threadIdx.x == 0) {
        double bce = acc[0] / ((double)BB * (double)CC);
        double result;
        if (*nmin > 0) {
            double crl = acc[1] - acc[2] + MARGIN;
            if (crl < 0.0) crl = 0.0;
            result = ALPHA * crl + (1.0 - ALPHA) * bce;
        } else {
            result = bce;
        }
        out[0] = (float)result;
    }
}

extern "C" void kernel_launch(void* const* d_in, const int* in_sizes, int n_in,
                              void* d_out, int out_size, void* d_ws, size_t ws_size,
                              hipStream_t stream) {
    const float* logits = (const float*)d_in[0];
    const float* target = (const float*)d_in[1];
    float* out = (float*)d_out;

    double* acc  = WS_ACC(d_ws);
    int* nmin    = WS_NMIN(d_ws);
    int* counts  = WS_COUNTS(d_ws);
    int* flags   = WS_FLAGS(d_ws);
    int* minor   = WS_MINOR(d_ws);
    int* posoff  = WS_POSOFF(d_ws);
    int* pcnt    = WS_PCNT(d_ws);
    float* posbuf = WS_POSBUF(d_ws);
    float* negblk = WS_NEGBLK(d_ws);

    init_kernel<<<20, 256, 0, stream>>>(acc, nmin, counts, pcnt);
    bce_counts_kernel<<<dim3(5, 256), 256, 0, stream>>>(logits, target, acc, counts);
    minority_flag_kernel<<<1250, 256, 0, stream>>>(counts, flags);
    compact_kernel<<<1, 256, 0, stream>>>(flags, counts, minor, nmin, posoff);
    crl_gather_kernel<<<dim3(64, NRB), 256, 0, stream>>>(logits, target, minor, nmin,
                                                         posoff, pcnt, posbuf, negblk);
    crl_reduce_kernel<<<64, 256, 0, stream>>>(nmin, posoff, posbuf, negblk, acc);
    finalize_kernel<<<1, 64, 0, stream>>>(acc, nmin, out);
}